// Round 7
// baseline (3407.075 us; speedup 1.0000x reference)
//
#include <hip/hip_runtime.h>
#include <math.h>

#define BATCH  16384
#define TSTEPS 19
#define INW    17
#define HID    128
#define NROW   64          // batch rows per WG -> grid = 256 = 1 block/CU
#define THREADS 1024       // 16 waves: wave halves split the m (batch) dim
#define KP     136         // padded row length (halfs) for h state (128+8)
#define KP0    40          // padded row length (halfs) for x (32+8)

typedef _Float16 f16x8 __attribute__((ext_vector_type(8)));
typedef float    f32x4 __attribute__((ext_vector_type(4)));

// ---- ws layout (halfs), MFMA-fragment-ordered tiles ----
#define W_BIG      0                 // 5 * 131072 = 655360
#define W_IH0      655360            // [512][32]: n_tile 0..31, tiles of 1024 (hi512|lo512)
#define W_HEAD     688128            // [32 rows][128]: (n_tile 0..1, ks 0..3) tiles of 1024
#define WS_HALFS   696320

__device__ __forceinline__ float fast_rcp(float x) { return __builtin_amdgcn_rcpf(x); }
__device__ __forceinline__ float sigm(float z)  { return fast_rcp(1.0f + __expf(-z)); }
__device__ __forceinline__ float tanh_(float z) { return 1.0f - 2.0f * fast_rcp(1.0f + __expf(2.0f * z)); }

// ---------------- weight conversion: fp32 -> f16 hi/lo, fragment order ----------------
__global__ void convert_w(const float* __restrict__ Whh0, const float* __restrict__ Whh1,
                          const float* __restrict__ Whh2, const float* __restrict__ Wih1,
                          const float* __restrict__ Wih2, const float* __restrict__ Wih0,
                          const float* __restrict__ Wl, _Float16* __restrict__ ws)
{
    int idx = blockIdx.x * 256 + threadIdx.x;
    if (idx < 327680) {
        int m = idx >> 16, e = idx & 65535;
        int r = e >> 7, k = e & 127;
        const float* src = (m == 0) ? Whh0 : (m == 1) ? Whh1 : (m == 2) ? Whh2
                          : (m == 3) ? Wih1 : Wih2;
        float v = src[e];
        _Float16 hi = (_Float16)v;
        int n_tile = r >> 4, colr = r & 15, ks = k >> 5, qd = (k >> 3) & 3, j = k & 7;
        int dst = W_BIG + m * 131072 + (n_tile * 4 + ks) * 1024 + (qd * 16 + colr) * 8 + j;
        ws[dst]       = hi;
        ws[dst + 512] = (_Float16)(v - (float)hi);
    } else if (idx < 344064) {
        int e = idx - 327680;              // [0, 16384)
        int r = e >> 5, k = e & 31;
        float v = (k < INW) ? Wih0[r * INW + k] : 0.0f;
        _Float16 hi = (_Float16)v;
        int n_tile = r >> 4, colr = r & 15, qd = k >> 3, j = k & 7;
        int dst = W_IH0 + n_tile * 1024 + (qd * 16 + colr) * 8 + j;
        ws[dst]       = hi;
        ws[dst + 512] = (_Float16)(v - (float)hi);
    } else if (idx < 348160) {
        int e = idx - 344064;              // [0, 4096)
        int r = e >> 7, k = e & 127;
        float v = (r < INW) ? Wl[(size_t)r * HID + k] : 0.0f;
        _Float16 hi = (_Float16)v;
        int n_tile = r >> 4, colr = r & 15, ks = k >> 5, qd = (k >> 3) & 3, j = k & 7;
        int dst = W_HEAD + (n_tile * 4 + ks) * 1024 + (qd * 16 + colr) * 8 + j;
        ws[dst]       = hi;
        ws[dst + 512] = (_Float16)(v - (float)hi);
    }
}

// ---------------- GEMM helpers ----------------
// acc[mi][g]: rows m = mg*32 + mi*16 + quad*4 + r, cols n = g*128 + jt*16 + col
// Ahi/Alo already point at the wave's 32-row group (&Hs[p][l][mg*32][0]).
__device__ __forceinline__ void gemm_h(f32x4 acc[2][4],
                                       const _Float16* __restrict__ Ahi,
                                       const _Float16* __restrict__ Alo,
                                       const _Float16* __restrict__ B,
                                       int col, int q8, int jt, int lane)
{
    const _Float16* a_h = Ahi + col * KP;
    const _Float16* a_l = Alo + col * KP;
    const int l8 = lane * 8;
#pragma unroll
    for (int ks = 0; ks < 4; ++ks) {
        const int ko = ks * 32 + q8;
        f16x8 ah0 = *(const f16x8*)(a_h + ko);
        f16x8 al0 = *(const f16x8*)(a_l + ko);
        f16x8 ah1 = *(const f16x8*)(a_h + 16 * KP + ko);
        f16x8 al1 = *(const f16x8*)(a_l + 16 * KP + ko);
#pragma unroll
        for (int g = 0; g < 4; ++g) {
            const _Float16* bt = B + ((g * 8 + jt) * 4 + ks) * 1024 + l8;
            f16x8 bh  = *(const f16x8*)(bt);
            f16x8 blo = *(const f16x8*)(bt + 512);
            acc[0][g] = __builtin_amdgcn_mfma_f32_16x16x32_f16(ah0, bh,  acc[0][g], 0, 0, 0);
            acc[0][g] = __builtin_amdgcn_mfma_f32_16x16x32_f16(al0, bh,  acc[0][g], 0, 0, 0);
            acc[0][g] = __builtin_amdgcn_mfma_f32_16x16x32_f16(ah0, blo, acc[0][g], 0, 0, 0);
            acc[1][g] = __builtin_amdgcn_mfma_f32_16x16x32_f16(ah1, bh,  acc[1][g], 0, 0, 0);
            acc[1][g] = __builtin_amdgcn_mfma_f32_16x16x32_f16(al1, bh,  acc[1][g], 0, 0, 0);
            acc[1][g] = __builtin_amdgcn_mfma_f32_16x16x32_f16(ah1, blo, acc[1][g], 0, 0, 0);
        }
    }
}

// x-part for layer 0: K=32 (padded); Xhi/Xlo point at wave's 32-row group
__device__ __forceinline__ void gemm_x(f32x4 acc[2][4],
                                       const _Float16* __restrict__ Xhi,
                                       const _Float16* __restrict__ Xlo,
                                       const _Float16* __restrict__ B,
                                       int col, int q8, int jt, int lane)
{
    const int l8 = lane * 8;
    f16x8 ah0 = *(const f16x8*)(Xhi + col * KP0 + q8);
    f16x8 al0 = *(const f16x8*)(Xlo + col * KP0 + q8);
    f16x8 ah1 = *(const f16x8*)(Xhi + (16 + col) * KP0 + q8);
    f16x8 al1 = *(const f16x8*)(Xlo + (16 + col) * KP0 + q8);
#pragma unroll
    for (int g = 0; g < 4; ++g) {
        const _Float16* bt = B + (g * 8 + jt) * 1024 + l8;
        f16x8 bh  = *(const f16x8*)(bt);
        f16x8 blo = *(const f16x8*)(bt + 512);
        acc[0][g] = __builtin_amdgcn_mfma_f32_16x16x32_f16(ah0, bh,  acc[0][g], 0, 0, 0);
        acc[0][g] = __builtin_amdgcn_mfma_f32_16x16x32_f16(al0, bh,  acc[0][g], 0, 0, 0);
        acc[0][g] = __builtin_amdgcn_mfma_f32_16x16x32_f16(ah0, blo, acc[0][g], 0, 0, 0);
        acc[1][g] = __builtin_amdgcn_mfma_f32_16x16x32_f16(ah1, bh,  acc[1][g], 0, 0, 0);
        acc[1][g] = __builtin_amdgcn_mfma_f32_16x16x32_f16(al1, bh,  acc[1][g], 0, 0, 0);
        acc[1][g] = __builtin_amdgcn_mfma_f32_16x16x32_f16(ah1, blo, acc[1][g], 0, 0, 0);
    }
}

__device__ __forceinline__ void acc_init(f32x4 acc[2][4], const float bs[4])
{
#pragma unroll
    for (int mi = 0; mi < 2; ++mi)
#pragma unroll
        for (int g = 0; g < 4; ++g) {
            float bv = bs[g];
            acc[mi][g] = (f32x4){bv, bv, bv, bv};
        }
}

// gate nonlinearity + h writeback; Hhi/Hlo point at the wave's 32-row group
__device__ __forceinline__ void gate_out(f32x4 acc[2][4], f32x4 (&cst)[2],
                                         _Float16* __restrict__ Hhi,
                                         _Float16* __restrict__ Hlo,
                                         int quad, int col, int jt)
{
#pragma unroll
    for (int mi = 0; mi < 2; ++mi) {
#pragma unroll
        for (int r = 0; r < 4; ++r) {
            float zi = acc[mi][0][r];
            float zf = acc[mi][1][r];
            float zg = acc[mi][2][r];
            float zo = acc[mi][3][r];
            float ig = sigm(zi), fg = sigm(zf), og = sigm(zo), gg = tanh_(zg);
            float cn = fg * cst[mi][r] + ig * gg;
            cst[mi][r] = cn;
            float h = og * tanh_(cn);
            int m = mi * 16 + quad * 4 + r;
            int j = jt * 16 + col;
            _Float16 hh = (_Float16)h;
            Hhi[m * KP + j] = hh;
            Hlo[m * KP + j] = (_Float16)(h - (float)hh);
        }
    }
}

// ---------------- main kernel ----------------
__global__ __launch_bounds__(THREADS) void lstm_mfma(
    const float* __restrict__ x,
    const float* __restrict__ bih0, const float* __restrict__ bhh0,
    const float* __restrict__ bih1, const float* __restrict__ bhh1,
    const float* __restrict__ bih2, const float* __restrict__ bhh2,
    const float* __restrict__ bl,
    const _Float16* __restrict__ wsp,
    float* __restrict__ out)
{
    __shared__ _Float16 Hs[2][3][NROW][KP];   // [hi/lo][layer][m][k]  = 104448 B
    __shared__ _Float16 Xs[2][NROW][KP0];     // [hi/lo][m][k]         = 10240 B

    const int tid  = threadIdx.x;
    const int wv   = tid >> 6;       // 0..15
    const int lane = tid & 63;
    const int col  = lane & 15;
    const int quad = lane >> 4;
    const int q8   = quad * 8;
    const int mg   = wv >> 3;        // 0 or 1: rows mg*32 .. mg*32+31
    const int jt   = wv & 7;         // j-tile: hidden units jt*16 + col
    const int b0   = blockIdx.x * NROW;
    const int rowoff = mg * 32 * KP;     // offset (halfs) into a H plane
    const int rowoffx = mg * 32 * KP0;   // offset into X plane

    // bias sums per layer for n = g*128 + jt*16 + col
    float bsum0[4], bsum1[4], bsum2[4];
#pragma unroll
    for (int g = 0; g < 4; ++g) {
        int n = g * 128 + jt * 16 + col;
        bsum0[g] = bih0[n] + bhh0[n];
        bsum1[g] = bih1[n] + bhh1[n];
        bsum2[g] = bih2[n] + bhh2[n];
    }

    // zero h state (hi+lo planes): 104448 B = 26112 floats
    for (int i = tid; i < 26112; i += THREADS) ((float*)Hs)[i] = 0.0f;

    // c state: 2 row-tiles x 4 rows = 8 floats per layer per thread
    f32x4 cst0[2], cst1[2], cst2[2];
#pragma unroll
    for (int mi = 0; mi < 2; ++mi) {
        cst0[mi] = (f32x4){0, 0, 0, 0};
        cst1[mi] = (f32x4){0, 0, 0, 0};
        cst2[mi] = (f32x4){0, 0, 0, 0};
    }

    // compile-time weight pointers
    const _Float16* Whh0p = wsp + W_BIG;
    const _Float16* Whh1p = wsp + W_BIG + 131072;
    const _Float16* Whh2p = wsp + W_BIG + 262144;
    const _Float16* Wih0p = wsp + W_IH0;
    const _Float16* Wih1p = wsp + W_BIG + 393216;
    const _Float16* Wih2p = wsp + W_BIG + 524288;

    // head bias (used by waves 0..7)
    float blv = 0.0f;
    {
        int i = (wv & 1) * 16 + col;
        if (i < INW) blv = bl[i];
    }

    __syncthreads();

#pragma unroll 1
    for (int t = 0; t < TSTEPS; ++t) {
        // ---- stage x[:, t, :] as f16 hi/lo (K padded to 32) ----
        for (int ii = tid; ii < NROW * 32; ii += THREADS) {
            int m = ii >> 5, k = ii & 31;
            float v = (k < INW) ? x[(size_t)(b0 + m) * (TSTEPS * INW) + t * INW + k] : 0.0f;
            _Float16 hi = (_Float16)v;
            Xs[0][m][k] = hi;
            Xs[1][m][k] = (_Float16)(v - (float)hi);
        }
        __syncthreads();

        // ================= layer 0 =================
        {
            f32x4 acc[2][4];
            acc_init(acc, bsum0);
            gemm_x(acc, &Xs[0][0][0] + rowoffx, &Xs[1][0][0] + rowoffx, Wih0p, col, q8, jt, lane);
            gemm_h(acc, &Hs[0][0][0][0] + rowoff, &Hs[1][0][0][0] + rowoff, Whh0p, col, q8, jt, lane);
            __syncthreads();
            gate_out(acc, cst0, &Hs[0][0][0][0] + rowoff, &Hs[1][0][0][0] + rowoff, quad, col, jt);
            __syncthreads();
        }
        // ================= layer 1 =================
        {
            f32x4 acc[2][4];
            acc_init(acc, bsum1);
            gemm_h(acc, &Hs[0][0][0][0] + rowoff, &Hs[1][0][0][0] + rowoff, Wih1p, col, q8, jt, lane);
            gemm_h(acc, &Hs[0][1][0][0] + rowoff, &Hs[1][1][0][0] + rowoff, Whh1p, col, q8, jt, lane);
            __syncthreads();
            gate_out(acc, cst1, &Hs[0][1][0][0] + rowoff, &Hs[1][1][0][0] + rowoff, quad, col, jt);
            __syncthreads();
        }
        // ================= layer 2 =================
        {
            f32x4 acc[2][4];
            acc_init(acc, bsum2);
            gemm_h(acc, &Hs[0][1][0][0] + rowoff, &Hs[1][1][0][0] + rowoff, Wih2p, col, q8, jt, lane);
            gemm_h(acc, &Hs[0][2][0][0] + rowoff, &Hs[1][2][0][0] + rowoff, Whh2p, col, q8, jt, lane);
            __syncthreads();
            gate_out(acc, cst2, &Hs[0][2][0][0] + rowoff, &Hs[1][2][0][0] + rowoff, quad, col, jt);
            __syncthreads();
        }

        // ---- head: out = h2 @ Wl^T + bl  (waves 0..7: mt = wv>>1, nt = wv&1) ----
        if (wv < 8) {
            const int mt = wv >> 1, nt = wv & 1;
            const _Float16* ah = &Hs[0][2][mt * 16 + col][0];
            const _Float16* al = &Hs[1][2][mt * 16 + col][0];
            f32x4 o = (f32x4){0, 0, 0, 0};
#pragma unroll
            for (int ks = 0; ks < 4; ++ks) {
                const _Float16* bt = wsp + W_HEAD + (nt * 4 + ks) * 1024 + lane * 8;
                f16x8 a_h = *(const f16x8*)(ah + ks * 32 + q8);
                f16x8 a_l = *(const f16x8*)(al + ks * 32 + q8);
                f16x8 b_h = *(const f16x8*)(bt);
                f16x8 b_l = *(const f16x8*)(bt + 512);
                o = __builtin_amdgcn_mfma_f32_16x16x32_f16(a_h, b_h, o, 0, 0, 0);
                o = __builtin_amdgcn_mfma_f32_16x16x32_f16(a_l, b_h, o, 0, 0, 0);
                o = __builtin_amdgcn_mfma_f32_16x16x32_f16(a_h, b_l, o, 0, 0, 0);
            }
            int i = nt * 16 + col;
            if (i < INW) {
#pragma unroll
                for (int r = 0; r < 4; ++r) {
                    int m = mt * 16 + quad * 4 + r;
                    out[(size_t)(b0 + m) * (TSTEPS * INW) + t * INW + i] = o[r] + blv;
                }
            }
        }
        __syncthreads();   // head reads of Hs[2] + Xs reuse fence before next t
    }
}

extern "C" void kernel_launch(void* const* d_in, const int* in_sizes, int n_in,
                              void* d_out, int out_size, void* d_ws, size_t ws_size,
                              hipStream_t stream) {
    const float* x    = (const float*)d_in[0];
    const float* Wih0 = (const float*)d_in[1];
    const float* Whh0 = (const float*)d_in[2];
    const float* bih0 = (const float*)d_in[3];
    const float* bhh0 = (const float*)d_in[4];
    const float* Wih1 = (const float*)d_in[5];
    const float* Whh1 = (const float*)d_in[6];
    const float* bih1 = (const float*)d_in[7];
    const float* bhh1 = (const float*)d_in[8];
    const float* Wih2 = (const float*)d_in[9];
    const float* Whh2 = (const float*)d_in[10];
    const float* bih2 = (const float*)d_in[11];
    const float* bhh2 = (const float*)d_in[12];
    const float* Wl   = (const float*)d_in[13];
    const float* bl   = (const float*)d_in[14];
    float* out = (float*)d_out;
    _Float16* ws = (_Float16*)d_ws;

    convert_w<<<(348160 + 255) / 256, 256, 0, stream>>>(Whh0, Whh1, Whh2, Wih1, Wih2, Wih0, Wl, ws);
    lstm_mfma<<<BATCH / NROW, THREADS, 0, stream>>>(
        x, bih0, bhh0, bih1, bhh1, bih2, bhh2, bl, ws, out);
}

// Round 8
// 808.211 us; speedup vs baseline: 4.2156x; 4.2156x over previous
//
#include <hip/hip_runtime.h>
#include <math.h>

#define BATCH  16384
#define TSTEPS 19
#define INW    17
#define HID    128
#define NROW   32          // batch rows per WG -> grid = 512 = 2 blocks/CU
#define THREADS 512        // 8 waves; wave wv owns j-tile wv (all 4 gates, both m-tiles)
#define KP     136         // padded row length (halfs) for h state (128+8)
#define KP0    40          // padded row length (halfs) for x (32+8)

typedef _Float16 f16x8 __attribute__((ext_vector_type(8)));
typedef float    f32x4 __attribute__((ext_vector_type(4)));

// ---- ws layout (halfs), MFMA-fragment-ordered tiles ----
// Big matrices (Whh0,Whh1,Whh2,Wih1,Wih2), each [512 rows][128 k]:
//   tile (n_tile 0..31, ks 0..3) = 1024 halfs: hi[512] | lo[512],
//   within plane: (quad*16 + col)*8 + j  -> lane*8 is coalesced.
#define W_BIG      0                 // 5 * 131072 = 655360
#define W_IH0      655360            // [512][32]: n_tile 0..31, tiles of 1024 (hi512|lo512)
#define W_HEAD     688128            // [32 rows][128]: (n_tile 0..1, ks 0..3) tiles of 1024
#define WS_HALFS   696320

__device__ __forceinline__ float fast_rcp(float x) { return __builtin_amdgcn_rcpf(x); }
__device__ __forceinline__ float sigm(float z)  { return fast_rcp(1.0f + __expf(-z)); }
__device__ __forceinline__ float tanh_(float z) { return 1.0f - 2.0f * fast_rcp(1.0f + __expf(2.0f * z)); }

// ---------------- weight conversion: fp32 -> f16 hi/lo, fragment order ----------------
__global__ void convert_w(const float* __restrict__ Whh0, const float* __restrict__ Whh1,
                          const float* __restrict__ Whh2, const float* __restrict__ Wih1,
                          const float* __restrict__ Wih2, const float* __restrict__ Wih0,
                          const float* __restrict__ Wl, _Float16* __restrict__ ws)
{
    int idx = blockIdx.x * 256 + threadIdx.x;
    if (idx < 327680) {
        int m = idx >> 16, e = idx & 65535;
        int r = e >> 7, k = e & 127;
        const float* src = (m == 0) ? Whh0 : (m == 1) ? Whh1 : (m == 2) ? Whh2
                          : (m == 3) ? Wih1 : Wih2;
        float v = src[e];
        _Float16 hi = (_Float16)v;
        int n_tile = r >> 4, colr = r & 15, ks = k >> 5, qd = (k >> 3) & 3, j = k & 7;
        int dst = W_BIG + m * 131072 + (n_tile * 4 + ks) * 1024 + (qd * 16 + colr) * 8 + j;
        ws[dst]       = hi;
        ws[dst + 512] = (_Float16)(v - (float)hi);
    } else if (idx < 344064) {
        int e = idx - 327680;              // [0, 16384)
        int r = e >> 5, k = e & 31;
        float v = (k < INW) ? Wih0[r * INW + k] : 0.0f;
        _Float16 hi = (_Float16)v;
        int n_tile = r >> 4, colr = r & 15, qd = k >> 3, j = k & 7;
        int dst = W_IH0 + n_tile * 1024 + (qd * 16 + colr) * 8 + j;
        ws[dst]       = hi;
        ws[dst + 512] = (_Float16)(v - (float)hi);
    } else if (idx < 348160) {
        int e = idx - 344064;              // [0, 4096)
        int r = e >> 7, k = e & 127;
        float v = (r < INW) ? Wl[(size_t)r * HID + k] : 0.0f;
        _Float16 hi = (_Float16)v;
        int n_tile = r >> 4, colr = r & 15, ks = k >> 5, qd = (k >> 3) & 3, j = k & 7;
        int dst = W_HEAD + (n_tile * 4 + ks) * 1024 + (qd * 16 + colr) * 8 + j;
        ws[dst]       = hi;
        ws[dst + 512] = (_Float16)(v - (float)hi);
    }
}

// ---------------- GEMM helpers ----------------
// acc[mt][g]: rows m = mt*16 + quad*4 + r, cols n = g*128 + wv*16 + col
// A from LDS h planes (hi/lo, row-major stride KP); B fragment tiles (coalesced lane*8).
__device__ __forceinline__ void gemm_h(f32x4 acc[2][4],
                                       const _Float16* __restrict__ Ahi,
                                       const _Float16* __restrict__ Alo,
                                       const _Float16* __restrict__ B,
                                       int col, int q8, int wv, int lane)
{
    const _Float16* a_h = Ahi + col * KP;
    const _Float16* a_l = Alo + col * KP;
    const int l8 = lane * 8;
#pragma unroll
    for (int ks = 0; ks < 4; ++ks) {
        const int ko = ks * 32 + q8;
        f16x8 ah0 = *(const f16x8*)(a_h + ko);
        f16x8 al0 = *(const f16x8*)(a_l + ko);
        f16x8 ah1 = *(const f16x8*)(a_h + 16 * KP + ko);
        f16x8 al1 = *(const f16x8*)(a_l + 16 * KP + ko);
#pragma unroll
        for (int g = 0; g < 4; ++g) {
            const _Float16* bt = B + ((g * 8 + wv) * 4 + ks) * 1024 + l8;
            f16x8 bh  = *(const f16x8*)(bt);
            f16x8 blo = *(const f16x8*)(bt + 512);
            acc[0][g] = __builtin_amdgcn_mfma_f32_16x16x32_f16(ah0, bh,  acc[0][g], 0, 0, 0);
            acc[0][g] = __builtin_amdgcn_mfma_f32_16x16x32_f16(al0, bh,  acc[0][g], 0, 0, 0);
            acc[0][g] = __builtin_amdgcn_mfma_f32_16x16x32_f16(ah0, blo, acc[0][g], 0, 0, 0);
            acc[1][g] = __builtin_amdgcn_mfma_f32_16x16x32_f16(ah1, bh,  acc[1][g], 0, 0, 0);
            acc[1][g] = __builtin_amdgcn_mfma_f32_16x16x32_f16(al1, bh,  acc[1][g], 0, 0, 0);
            acc[1][g] = __builtin_amdgcn_mfma_f32_16x16x32_f16(ah1, blo, acc[1][g], 0, 0, 0);
        }
    }
}

// x-part for layer 0: K=32 (padded)
__device__ __forceinline__ void gemm_x(f32x4 acc[2][4],
                                       const _Float16* __restrict__ Xhi,
                                       const _Float16* __restrict__ Xlo,
                                       const _Float16* __restrict__ B,
                                       int col, int q8, int wv, int lane)
{
    const int l8 = lane * 8;
    f16x8 ah0 = *(const f16x8*)(Xhi + col * KP0 + q8);
    f16x8 al0 = *(const f16x8*)(Xlo + col * KP0 + q8);
    f16x8 ah1 = *(const f16x8*)(Xhi + (16 + col) * KP0 + q8);
    f16x8 al1 = *(const f16x8*)(Xlo + (16 + col) * KP0 + q8);
#pragma unroll
    for (int g = 0; g < 4; ++g) {
        const _Float16* bt = B + (g * 8 + wv) * 1024 + l8;
        f16x8 bh  = *(const f16x8*)(bt);
        f16x8 blo = *(const f16x8*)(bt + 512);
        acc[0][g] = __builtin_amdgcn_mfma_f32_16x16x32_f16(ah0, bh,  acc[0][g], 0, 0, 0);
        acc[0][g] = __builtin_amdgcn_mfma_f32_16x16x32_f16(al0, bh,  acc[0][g], 0, 0, 0);
        acc[0][g] = __builtin_amdgcn_mfma_f32_16x16x32_f16(ah0, blo, acc[0][g], 0, 0, 0);
        acc[1][g] = __builtin_amdgcn_mfma_f32_16x16x32_f16(ah1, bh,  acc[1][g], 0, 0, 0);
        acc[1][g] = __builtin_amdgcn_mfma_f32_16x16x32_f16(al1, bh,  acc[1][g], 0, 0, 0);
        acc[1][g] = __builtin_amdgcn_mfma_f32_16x16x32_f16(ah1, blo, acc[1][g], 0, 0, 0);
    }
}

// ---------------- main kernel ----------------
__global__ __launch_bounds__(THREADS, 2) void lstm_mfma(
    const float* __restrict__ x,
    const float* __restrict__ bih0, const float* __restrict__ bhh0,
    const float* __restrict__ bih1, const float* __restrict__ bhh1,
    const float* __restrict__ bih2, const float* __restrict__ bhh2,
    const float* __restrict__ bl,
    const _Float16* __restrict__ wsp,
    float* __restrict__ out)
{
    __shared__ _Float16 Hs[2][3][NROW][KP];   // [hi/lo][layer][m][k]  = 52224 B
    __shared__ _Float16 Xs[2][NROW][KP0];     // [hi/lo][m][k]         = 5120 B
    __shared__ float    Bs[3][512];           // bih+bhh per layer     = 6144 B

    const int tid  = threadIdx.x;
    const int wv   = tid >> 6;
    const int lane = tid & 63;
    const int col  = lane & 15;
    const int quad = lane >> 4;
    const int q8   = quad * 8;
    const int b0   = blockIdx.x * NROW;

    // stage bias sums into LDS (saves persistent registers)
    for (int i = tid; i < 1536; i += THREADS) {
        int l = i >> 9, n = i & 511;
        const float* bi = (l == 0) ? bih0 : (l == 1) ? bih1 : bih2;
        const float* bh = (l == 0) ? bhh0 : (l == 1) ? bhh1 : bhh2;
        Bs[l][n] = bi[n] + bh[n];
    }
    // zero h state (hi+lo planes): 52224 B = 13056 floats
    for (int i = tid; i < 13056; i += THREADS) ((float*)Hs)[i] = 0.0f;

    f32x4 cst[3][2];
#pragma unroll
    for (int l = 0; l < 3; ++l) { cst[l][0] = (f32x4){0,0,0,0}; cst[l][1] = (f32x4){0,0,0,0}; }

    // weight pointers (fragment-ordered)
    const _Float16* Whh[3] = {wsp + W_BIG,  wsp + W_BIG + 131072, wsp + W_BIG + 262144};
    const _Float16* Wih[3] = {wsp + W_IH0, wsp + W_BIG + 393216, wsp + W_BIG + 524288};

    // head bias (waves 0..3 only)
    float blv = 0.0f;
    {
        int i = (wv & 1) * 16 + col;
        if (wv < 4 && i < INW) blv = bl[i];
    }

    __syncthreads();

#pragma unroll 1
    for (int t = 0; t < TSTEPS; ++t) {
        // ---- stage x[:, t, :] as f16 hi/lo (K padded to 32) ----
        for (int ii = tid; ii < NROW * 32; ii += THREADS) {
            int m = ii >> 5, k = ii & 31;
            float v = (k < INW) ? x[(size_t)(b0 + m) * (TSTEPS * INW) + t * INW + k] : 0.0f;
            _Float16 hi = (_Float16)v;
            Xs[0][m][k] = hi;
            Xs[1][m][k] = (_Float16)(v - (float)hi);
        }
        __syncthreads();

#pragma unroll 1
        for (int l = 0; l < 3; ++l) {
            f32x4 acc[2][4];
#pragma unroll
            for (int mt = 0; mt < 2; ++mt)
#pragma unroll
                for (int g = 0; g < 4; ++g) {
                    float bv = Bs[l][g * 128 + wv * 16 + col];
                    acc[mt][g] = (f32x4){bv, bv, bv, bv};
                }

            // input contribution
            if (l == 0)
                gemm_x(acc, &Xs[0][0][0], &Xs[1][0][0], Wih[0], col, q8, wv, lane);
            else
                gemm_h(acc, &Hs[0][l - 1][0][0], &Hs[1][l - 1][0][0], Wih[l], col, q8, wv, lane);
            // recurrent contribution
            gemm_h(acc, &Hs[0][l][0][0], &Hs[1][l][0][0], Whh[l], col, q8, wv, lane);

            __syncthreads();   // all reads of Hs[l] (and Hs[l-1]) complete

            // gates fully in-register; write new h (hi/lo) to LDS
#pragma unroll
            for (int mt = 0; mt < 2; ++mt) {
#pragma unroll
                for (int r = 0; r < 4; ++r) {
                    float zi = acc[mt][0][r];
                    float zf = acc[mt][1][r];
                    float zg = acc[mt][2][r];
                    float zo = acc[mt][3][r];
                    float ig = sigm(zi), fg = sigm(zf), og = sigm(zo), gg = tanh_(zg);
                    float cn = fg * cst[l][mt][r] + ig * gg;
                    cst[l][mt][r] = cn;
                    float h = og * tanh_(cn);
                    int m = mt * 16 + quad * 4 + r;
                    int j = wv * 16 + col;
                    _Float16 hh = (_Float16)h;
                    Hs[0][l][m][j] = hh;
                    Hs[1][l][m][j] = (_Float16)(h - (float)hh);
                }
            }
            __syncthreads();   // new h visible
        }

        // ---- head: out = h2 @ Wl^T + bl  (waves 0..3: mt = wv>>1, nt = wv&1) ----
        if (wv < 4) {
            const int mt = wv >> 1, nt = wv & 1;
            const _Float16* ah = &Hs[0][2][mt * 16 + col][0];
            const _Float16* al = &Hs[1][2][mt * 16 + col][0];
            f32x4 o = (f32x4){0, 0, 0, 0};
#pragma unroll
            for (int ks = 0; ks < 4; ++ks) {
                const _Float16* bt = wsp + W_HEAD + (nt * 4 + ks) * 1024 + lane * 8;
                f16x8 a_h = *(const f16x8*)(ah + ks * 32 + q8);
                f16x8 a_l = *(const f16x8*)(al + ks * 32 + q8);
                f16x8 b_h = *(const f16x8*)(bt);
                f16x8 b_l = *(const f16x8*)(bt + 512);
                o = __builtin_amdgcn_mfma_f32_16x16x32_f16(a_h, b_h, o, 0, 0, 0);
                o = __builtin_amdgcn_mfma_f32_16x16x32_f16(a_l, b_h, o, 0, 0, 0);
                o = __builtin_amdgcn_mfma_f32_16x16x32_f16(a_h, b_l, o, 0, 0, 0);
            }
            int i = nt * 16 + col;
            if (i < INW) {
#pragma unroll
                for (int r = 0; r < 4; ++r) {
                    int m = mt * 16 + quad * 4 + r;
                    out[(size_t)(b0 + m) * (TSTEPS * INW) + t * INW + i] = o[r] + blv;
                }
            }
        }
        __syncthreads();   // head reads of Hs[2] + Xs reuse fence before next t
    }
}

extern "C" void kernel_launch(void* const* d_in, const int* in_sizes, int n_in,
                              void* d_out, int out_size, void* d_ws, size_t ws_size,
                              hipStream_t stream) {
    const float* x    = (const float*)d_in[0];
    const float* Wih0 = (const float*)d_in[1];
    const float* Whh0 = (const float*)d_in[2];
    const float* bih0 = (const float*)d_in[3];
    const float* bhh0 = (const float*)d_in[4];
    const float* Wih1 = (const float*)d_in[5];
    const float* Whh1 = (const float*)d_in[6];
    const float* bih1 = (const float*)d_in[7];
    const float* bhh1 = (const float*)d_in[8];
    const float* Wih2 = (const float*)d_in[9];
    const float* Whh2 = (const float*)d_in[10];
    const float* bih2 = (const float*)d_in[11];
    const float* bhh2 = (const float*)d_in[12];
    const float* Wl   = (const float*)d_in[13];
    const float* bl   = (const float*)d_in[14];
    float* out = (float*)d_out;
    _Float16* ws = (_Float16*)d_ws;

    convert_w<<<(348160 + 255) / 256, 256, 0, stream>>>(Whh0, Whh1, Whh2, Wih1, Wih2, Wih0, Wl, ws);
    lstm_mfma<<<BATCH / NROW, THREADS, 0, stream>>>(
        x, bih0, bhh0, bih1, bhh1, bih2, bhh2, bl, ws, out);
}